// Round 9
// baseline (879.011 us; speedup 1.0000x reference)
//
#include <hip/hip_runtime.h>

#define BB 2
#define NN 4096
#define CC 256
#define FF 1024
#define NLAYER 4
#define RR (BB*NN)
#define SPL 8            // n/m split for attention passes
#define QKLD (3*CC)      // qkv packed row stride = 768
#define NEG_BIG (-1e30f)

typedef _Float16 h16;
typedef __attribute__((ext_vector_type(8))) _Float16 half8;
typedef __attribute__((ext_vector_type(4))) float f32x4;
typedef __attribute__((ext_vector_type(16))) float f32x16;

// ---------------- async global->LDS, 16B per lane ----------------
__device__ __forceinline__ void gload16(const h16* g, h16* l) {
    __builtin_amdgcn_global_load_lds((const __attribute__((address_space(1))) void*)g,
                                     (__attribute__((address_space(3))) void*)l, 16, 0, 0);
}

// stage ROWS x 64 h16 chunk into lds[ROWS][64] with piece-XOR swizzle
template<int ROWS>
__device__ __forceinline__ void stage_rows(const h16* __restrict__ src, int ld,
    int row0, int c0, h16* lds, int tid)
{
    int w = tid >> 6;
    #pragma unroll
    for (int t = 0; t < ROWS/32; ++t) {
        int slot = t*256 + tid;
        int row = slot >> 3;
        int pp  = slot & 7;
        int piece = pp ^ (row & 7);
        gload16(src + (size_t)(row0 + row)*ld + c0 + piece*8,
                lds + (t*256 + w*64)*8);
    }
}

// read 8 contiguous h16 (logical k-piece pl) of LDS row
__device__ __forceinline__ half8 frag_ld(const h16* lds, int row, int pl) {
    return *(const half8*)(lds + row*64 + ((pl ^ (row & 7))*8));
}

// ---------------- weight transpose+convert: W[K,N] f32 -> WT[N,K] f16 ----------------
__global__ __launch_bounds__(256) void pct_wtrans(const float* __restrict__ W,
    h16* __restrict__ WT, int K, int N, int dstride)
{
    __shared__ h16 t[32][33];
    const float* Wl = W + (size_t)blockIdx.z*K*N;
    h16* WTl = WT + (size_t)blockIdx.z*dstride;
    int k0 = blockIdx.x*32, n0 = blockIdx.y*32;
    int tx = threadIdx.x & 31, ty = threadIdx.x >> 5;
    #pragma unroll
    for (int i = ty; i < 32; i += 8)
        t[i][tx] = (h16)Wl[(size_t)(k0+i)*N + n0 + tx];
    __syncthreads();
    #pragma unroll
    for (int i = ty; i < 32; i += 8)
        WTl[(size_t)(n0+i)*K + k0 + tx] = t[tx][i];
}

// ---------------- pack q/k/v biases into [NLAYER][768] ----------------
__global__ __launch_bounds__(256) void pct_bias3(const float* __restrict__ bq,
    const float* __restrict__ bk, const float* __restrict__ bv, float* __restrict__ o)
{
    int l = blockIdx.x, c = threadIdx.x;
    o[l*QKLD + c]        = bq[l*CC + c];
    o[l*QKLD + CC + c]   = bk[l*CC + c];
    o[l*QKLD + 2*CC + c] = bv[l*CC + c];
}

// ---------------- embed: [B,N,3] @ [3,256] + b -> f16 ----------------
__global__ __launch_bounds__(256) void pct_embed(const float* __restrict__ inp,
    const float* __restrict__ w0, const float* __restrict__ b0, h16* __restrict__ out)
{
    int r = blockIdx.x, c = threadIdx.x;
    float a0 = inp[r*3+0], a1 = inp[r*3+1], a2 = inp[r*3+2];
    out[(size_t)r*CC + c] = (h16)(b0[c] + a0*w0[c] + a1*w0[CC+c] + a2*w0[2*CC+c]);
}

// ---------------- column stats over points axis (half8 vectorized) ----------------
__global__ __launch_bounds__(256) void pct_colstat(const h16* __restrict__ x, int ldx,
    float* __restrict__ sums)
{
    __shared__ float red[2][8][256];
    int b = blockIdx.x, blk = blockIdx.y;
    int rt = threadIdx.x >> 5;
    int cg = (threadIdx.x & 31) * 8;
    const h16* p = x + ((size_t)b*NN + (size_t)blk*64 + rt)*ldx + cg;
    float s1[8] = {0,0,0,0,0,0,0,0}, s2[8] = {0,0,0,0,0,0,0,0};
    #pragma unroll
    for (int i = 0; i < 8; ++i) {
        half8 v = *(const half8*)(p + (size_t)i*8*ldx);
        #pragma unroll
        for (int j = 0; j < 8; ++j) { float f = (float)v[j]; s1[j] += f; s2[j] += f*f; }
    }
    #pragma unroll
    for (int j = 0; j < 8; ++j) { red[0][rt][cg+j] = s1[j]; red[1][rt][cg+j] = s2[j]; }
    __syncthreads();
    int c = threadIdx.x;
    float t1 = 0.f, t2 = 0.f;
    #pragma unroll
    for (int r = 0; r < 8; ++r) { t1 += red[0][r][c]; t2 += red[1][r][c]; }
    atomicAdd(&sums[(b*CC + c)*2 + 0], t1);
    atomicAdd(&sums[(b*CC + c)*2 + 1], t2);
}

// ---------------- apply LN (stats over points), optional relu + residual (half8) ----------------
__global__ __launch_bounds__(256) void pct_lnapply(const h16* __restrict__ x, int ldx,
    const float* __restrict__ sums, const float* __restrict__ scale, const float* __restrict__ bias,
    const h16* __restrict__ res, int ldr, h16* __restrict__ out, int ldo,
    int do_relu)
{
    int r = blockIdx.x*8 + (threadIdx.x >> 5);
    int cg = (threadIdx.x & 31) * 8;
    int b = r / NN;
    half8 xv = *(const half8*)(x + (size_t)r*ldx + cg);
    half8 rv;
    if (res) rv = *(const half8*)(res + (size_t)r*ldr + cg);
    half8 ov;
    #pragma unroll
    for (int j = 0; j < 8; ++j) {
        int c = cg + j;
        float s1 = sums[(b*CC + c)*2], s2 = sums[(b*CC + c)*2 + 1];
        float mu  = s1 * (1.f/NN);
        float var = s2 * (1.f/NN) - mu*mu;
        float rstd = rsqrtf(var + 1e-6f);
        float y = ((float)xv[j] - mu) * rstd * scale[c] + bias[c];
        if (do_relu) y = fmaxf(y, 0.f);
        if (res) y += (float)rv[j];
        ov[j] = (h16)y;
    }
    *(half8*)(out + (size_t)r*ldo + cg) = ov;
}

// ---------------- f16 MFMA GEMM (NT): out[m,n] = rowS(m)*(sum_k A[m,k]*WT[n,k]) + bias[n] ----------------
template<int BN, bool OUT_F32>
__global__ __launch_bounds__(256) void pct_gemm_f16(
    const h16* __restrict__ A, int lda,
    const h16* __restrict__ WT, const float* __restrict__ bias,
    void* __restrict__ outp, int ldo, int K, const float* __restrict__ rowS)
{
    constexpr int BJ = BN/2;
    constexpr int NF = BJ/16;
    __shared__ __align__(16) h16 Asm[128*64];
    __shared__ __align__(16) h16 Bsm[BN*64];
    const int tid = threadIdx.x;
    const int lane = tid & 63, w = tid >> 6;
    const int ln = lane & 15, lq = lane >> 4;
    const int wr = w >> 1, wc = w & 1;
    const int m0 = blockIdx.x*128, n0 = blockIdx.y*BN;
    f32x4 acc[4][NF];
    #pragma unroll
    for (int i = 0; i < 4; ++i)
        #pragma unroll
        for (int j = 0; j < NF; ++j) acc[i][j] = (f32x4){0.f,0.f,0.f,0.f};
    for (int k0 = 0; k0 < K; k0 += 64) {
        stage_rows<128>(A, lda, m0, k0, Asm, tid);
        stage_rows<BN>(WT, K, n0, k0, Bsm, tid);
        __syncthreads();
        #pragma unroll
        for (int kk = 0; kk < 2; ++kk) {
            half8 af[4], bfr[NF];
            #pragma unroll
            for (int i = 0; i < 4; ++i) af[i] = frag_ld(Asm, wr*64 + i*16 + ln, kk*4 + lq);
            #pragma unroll
            for (int j = 0; j < NF; ++j) bfr[j] = frag_ld(Bsm, wc*BJ + j*16 + ln, kk*4 + lq);
            #pragma unroll
            for (int i = 0; i < 4; ++i)
                #pragma unroll
                for (int j = 0; j < NF; ++j)
                    acc[i][j] = __builtin_amdgcn_mfma_f32_16x16x32_f16(af[i], bfr[j], acc[i][j], 0, 0, 0);
        }
        __syncthreads();
    }
    #pragma unroll
    for (int j = 0; j < NF; ++j) {
        int col = n0 + wc*BJ + j*16 + ln;
        float bv = bias[col];
        #pragma unroll
        for (int i = 0; i < 4; ++i) {
            #pragma unroll
            for (int r = 0; r < 4; ++r) {
                int row = m0 + wr*64 + i*16 + lq*4 + r;
                float sc = 1.f;
                if (rowS) { float s = rowS[row]; sc = s / (1e-9f + s); }
                float v = acc[i][j][r] * sc + bv;
                if (OUT_F32) ((float*)outp)[(size_t)row*ldo + col] = v;
                else ((h16*)outp)[(size_t)row*ldo + col] = (h16)v;
            }
        }
    }
}

// ---------------- pass A: row max/sumexp of Q@K^T.  NO LDS, NO barriers. ----------------
// grid (BB, NN/128, SPL); 4 waves; wave owns 32 m-rows (A-slice in 64 VGPRs), streams K from global.
__global__ __launch_bounds__(256) void attn_rowstats(const h16* __restrict__ QKV,
    float2* __restrict__ part)
{
    const int b = blockIdx.x, mt = blockIdx.y, sp = blockIdx.z;
    const int tid = threadIdx.x;
    const int lane = tid & 63, wr = tid >> 6;
    const int ln2 = lane & 31, h = lane >> 5;
    const h16* qb = QKV + (size_t)b*NN*QKLD;
    const h16* kb = qb + CC;
    const int m0 = mt*128;
    // A slice resident in registers: my row, all K=256 (16 slices of 16, this lane's h-half)
    const h16* qrow = qb + (size_t)(m0 + wr*32 + ln2)*QKLD + h*8;
    half8 qreg[16];
    #pragma unroll
    for (int kk = 0; kk < 16; ++kk) qreg[kk] = *(const half8*)(qrow + kk*16);

    float rm[16], rs[16];
    #pragma unroll
    for (int g = 0; g < 16; ++g) { rm[g] = NEG_BIG; rs[g] = 0.f; }

    const int nbeg = sp*(NN/SPL);
    for (int n0 = nbeg; n0 < nbeg + NN/SPL; n0 += 128) {
        f32x16 acc[4];
        #pragma unroll
        for (int j = 0; j < 4; ++j) acc[j] = (f32x16)(0.f);
        const h16* kt = kb + (size_t)(n0 + ln2)*QKLD + h*8;
        #pragma unroll
        for (int kk = 0; kk < 16; ++kk) {
            #pragma unroll
            for (int j = 0; j < 4; ++j) {
                half8 bf = *(const half8*)(kt + (size_t)(j*32)*QKLD + kk*16);
                acc[j] = __builtin_amdgcn_mfma_f32_32x32x16_f16(qreg[kk], bf, acc[j], 0, 0, 0);
            }
        }
        // online row stats: per g (fixed row), 4 cols (j)
        #pragma unroll
        for (int g = 0; g < 16; ++g) {
            float a0 = acc[0][g], a1 = acc[1][g], a2 = acc[2][g], a3 = acc[3][g];
            float tm = fmaxf(fmaxf(a0,a1), fmaxf(a2,a3));
            float m = rm[g];
            if (tm > m) { rs[g] *= __expf(m - tm); m = tm; rm[g] = tm; }
            rs[g] += __expf(a0-m) + __expf(a1-m) + __expf(a2-m) + __expf(a3-m);
        }
    }
    // reduce across the 32 col-lanes (masks<=16 preserve the h bit = row group)
    #pragma unroll
    for (int g = 0; g < 16; ++g) {
        float m = rm[g], s = rs[g];
        #pragma unroll
        for (int msk = 1; msk <= 16; msk <<= 1) {
            float mo = __shfl_xor(m, msk, 64);
            float so = __shfl_xor(s, msk, 64);
            float mn = fmaxf(m, mo);
            s = s*__expf(m-mn) + so*__expf(mo-mn);
            m = mn;
        }
        if (ln2 == 0) {
            int row = m0 + wr*32 + (g & 3) + 8*(g >> 2) + 4*h;
            part[((size_t)b*NN + row)*SPL + sp] = make_float2(m, s);
        }
    }
}

// ---------------- combine SPL split row stats; store (rmax, 1/rsum) ----------------
__global__ __launch_bounds__(256) void pct_rowcomb(const float2* __restrict__ part,
    float2* __restrict__ rstat)
{
    int idx = blockIdx.x*256 + threadIdx.x;
    const float2* p = part + (size_t)idx*SPL;
    float m = NEG_BIG;
    #pragma unroll
    for (int s = 0; s < SPL; ++s) m = fmaxf(m, p[s].x);
    float sum = 0.f;
    #pragma unroll
    for (int s = 0; s < SPL; ++s) sum += p[s].y * __expf(p[s].x - m);
    rstat[idx] = make_float2(m, 1.0f / sum);
}

// ---------------- pass B: column sums of softmax.  NO LDS, NO barriers. ----------------
// grid (BB, NN/128, SPL); wave owns 32 n-rows of K (regs), streams Q; acc = S^T tile.
__global__ __launch_bounds__(256) void attn_colsums(const h16* __restrict__ QKV,
    const float2* __restrict__ rstat, float* __restrict__ S)
{
    const int b = blockIdx.x, nt = blockIdx.y, sp = blockIdx.z;
    const int tid = threadIdx.x;
    const int lane = tid & 63, wr = tid >> 6;
    const int ln2 = lane & 31, h = lane >> 5;
    const h16* qb = QKV + (size_t)b*NN*QKLD;
    const h16* kb = qb + CC;
    const float2* rst = rstat + (size_t)b*NN;
    const int n0 = nt*128;
    const h16* krow = kb + (size_t)(n0 + wr*32 + ln2)*QKLD + h*8;
    half8 kreg[16];
    #pragma unroll
    for (int kk = 0; kk < 16; ++kk) kreg[kk] = *(const half8*)(krow + kk*16);

    float cs[16];
    #pragma unroll
    for (int g = 0; g < 16; ++g) cs[g] = 0.f;

    const int mbeg = sp*(NN/SPL);
    for (int m0 = mbeg; m0 < mbeg + NN/SPL; m0 += 128) {
        f32x16 acc[4];
        #pragma unroll
        for (int j = 0; j < 4; ++j) acc[j] = (f32x16)(0.f);
        const h16* qt = qb + (size_t)(m0 + ln2)*QKLD + h*8;
        #pragma unroll
        for (int kk = 0; kk < 16; ++kk) {
            #pragma unroll
            for (int j = 0; j < 4; ++j) {
                half8 bf = *(const half8*)(qt + (size_t)(j*32)*QKLD + kk*16);
                acc[j] = __builtin_amdgcn_mfma_f32_32x32x16_f16(kreg[kk], bf, acc[j], 0, 0, 0);
            }
        }
        #pragma unroll
        for (int j = 0; j < 4; ++j) {
            float2 st = rst[m0 + j*32 + ln2];
            #pragma unroll
            for (int g = 0; g < 16; ++g)
                cs[g] += __expf(acc[j][g] - st.x) * st.y;
        }
    }
    #pragma unroll
    for (int g = 0; g < 16; ++g) {
        float s = cs[g];
        #pragma unroll
        for (int msk = 1; msk <= 16; msk <<= 1)
            s += __shfl_xor(s, msk, 64);
        if (ln2 == 0) {
            int row = n0 + wr*32 + (g & 3) + 8*(g >> 2) + 4*h;
            atomicAdd(&S[(size_t)b*NN + row], s);
        }
    }
}

extern "C" void kernel_launch(void* const* d_in, const int* in_sizes, int n_in,
                              void* d_out, int out_size, void* d_ws, size_t ws_size,
                              hipStream_t stream)
{
    const float* inp  = (const float*)d_in[0];
    const float* w0   = (const float*)d_in[1];
    const float* b0   = (const float*)d_in[2];
    const float* ln0s = (const float*)d_in[3];
    const float* ln0b = (const float*)d_in[4];
    const float* w1   = (const float*)d_in[5];
    const float* b1   = (const float*)d_in[6];
    const float* ln1s = (const float*)d_in[7];
    const float* ln1b = (const float*)d_in[8];
    const float* wq   = (const float*)d_in[9];
    const float* bq   = (const float*)d_in[10];
    const float* wk   = (const float*)d_in[11];
    const float* bk   = (const float*)d_in[12];
    const float* wv   = (const float*)d_in[13];
    const float* bv   = (const float*)d_in[14];
    const float* wo   = (const float*)d_in[15];
    const float* bo   = (const float*)d_in[16];
    const float* alns = (const float*)d_in[17];
    const float* alnb = (const float*)d_in[18];
    const float* wf   = (const float*)d_in[19];
    const float* bfb  = (const float*)d_in[20];
    float* out = (float*)d_out;

    // workspace layout
    char* p = (char*)d_ws;
    auto alloc = [&](size_t bytes) { char* r = p; p += (bytes + 255) & ~255ULL; return r; };
    h16* t0    = (h16*)alloc((size_t)RR*CC*2);
    h16* t1    = (h16*)alloc((size_t)RR*CC*2);
    h16* t2    = (h16*)alloc((size_t)RR*CC*2);
    h16* x1    = (h16*)alloc((size_t)RR*CC*2);
    h16* qkv   = (h16*)alloc((size_t)RR*QKLD*2);
    h16* oh    = (h16*)alloc((size_t)RR*CC*2);
    h16* xcat  = (h16*)alloc((size_t)RR*FF*2);
    h16* w1T   = (h16*)alloc((size_t)CC*CC*2);
    h16* wqkvT = (h16*)alloc((size_t)NLAYER*QKLD*CC*2);
    h16* woT   = (h16*)alloc((size_t)NLAYER*CC*CC*2);
    h16* wfT   = (h16*)alloc((size_t)FF*FF*2);
    float* bqkv  = (float*)alloc((size_t)NLAYER*QKLD*4);
    float2* part  = (float2*)alloc((size_t)RR*SPL*8);
    float2* rstat = (float2*)alloc((size_t)RR*8);
    float* Ssum  = (float*)alloc((size_t)NLAYER*RR*4);   // zeroed below
    float* lns   = (float*)alloc((size_t)6*BB*CC*2*4);   // zeroed below (adjacent)

    dim3 blk(256);

    // zero Ssum..lns span in one memset (adjacent in layout)
    hipMemsetAsync(Ssum, 0, (size_t)((char*)(lns + 6*BB*CC*2) - (char*)Ssum), stream);

    // weight transpose+convert (+pack q/k/v)
    pct_wtrans<<<dim3(CC/32, CC/32, 1), blk, 0, stream>>>(w1, w1T, CC, CC, CC*CC);
    pct_wtrans<<<dim3(CC/32, CC/32, NLAYER), blk, 0, stream>>>(wq, wqkvT,            CC, CC, QKLD*CC);
    pct_wtrans<<<dim3(CC/32, CC/32, NLAYER), blk, 0, stream>>>(wk, wqkvT + CC*CC,    CC, CC, QKLD*CC);
    pct_wtrans<<<dim3(CC/32, CC/32, NLAYER), blk, 0, stream>>>(wv, wqkvT + 2*CC*CC,  CC, CC, QKLD*CC);
    pct_wtrans<<<dim3(CC/32, CC/32, NLAYER), blk, 0, stream>>>(wo, woT, CC, CC, CC*CC);
    pct_wtrans<<<dim3(FF/32, FF/32, 1), blk, 0, stream>>>(wf, wfT, FF, FF, FF*FF);
    pct_bias3<<<NLAYER, blk, 0, stream>>>(bq, bk, bv, bqkv);

    // pre-conv stack
    pct_embed<<<RR, blk, 0, stream>>>(inp, w0, b0, t0);
    pct_colstat<<<dim3(BB,64), blk, 0, stream>>>(t0, CC, lns + 0*BB*CC*2);
    pct_lnapply<<<RR/8, blk, 0, stream>>>(t0, CC, lns + 0*BB*CC*2, ln0s, ln0b, nullptr, 0, t1, CC, 0);
    pct_gemm_f16<64,false><<<dim3(RR/128, CC/64), blk, 0, stream>>>(t1, CC, w1T, b1, t2, CC, CC, nullptr);
    pct_colstat<<<dim3(BB,64), blk, 0, stream>>>(t2, CC, lns + 1*BB*CC*2);
    pct_lnapply<<<RR/8, blk, 0, stream>>>(t2, CC, lns + 1*BB*CC*2, ln1s, ln1b, nullptr, 0, x1, CC, 0);

    const h16* xin = x1; int ldx = CC;
    for (int i = 0; i < NLAYER; ++i) {
        // fused q/k/v GEMM -> qkv[RR][768]
        pct_gemm_f16<64,false><<<dim3(RR/128, QKLD/64), blk, 0, stream>>>(
            xin, ldx, wqkvT + (size_t)i*QKLD*CC, bqkv + i*QKLD, qkv, QKLD, CC, nullptr);

        attn_rowstats<<<dim3(BB, NN/128, SPL), blk, 0, stream>>>(qkv, part);
        pct_rowcomb<<<RR/256, blk, 0, stream>>>(part, rstat);
        attn_colsums<<<dim3(BB, NN/128, SPL), blk, 0, stream>>>(qkv, rstat, Ssum + (size_t)i*RR);

        // wo GEMM on v (rows scaled by col[m] in epilogue)
        pct_gemm_f16<64,false><<<dim3(RR/128, CC/64), blk, 0, stream>>>(
            qkv + 2*CC, QKLD, woT + (size_t)i*CC*CC, bo + i*CC, oh, CC, CC, Ssum + (size_t)i*RR);

        pct_colstat<<<dim3(BB,64), blk, 0, stream>>>(oh, CC, lns + (2+i)*BB*CC*2);
        pct_lnapply<<<RR/8, blk, 0, stream>>>(oh, CC, lns + (2+i)*BB*CC*2, alns + i*CC, alnb + i*CC,
                                              xin, ldx, xcat + i*CC, FF, 1);
        xin = xcat + i*CC; ldx = FF;
    }

    pct_gemm_f16<128,true><<<dim3(RR/128, FF/128), blk, 0, stream>>>(xcat, FF, wfT, bfb, out, FF, FF, nullptr);
}

// Round 10
// 536.225 us; speedup vs baseline: 1.6393x; 1.6393x over previous
//
#include <hip/hip_runtime.h>

#define BB 2
#define NN 4096
#define CC 256
#define FF 1024
#define NLAYER 4
#define RR (BB*NN)
#define SPL 16           // n/m split for attention passes
#define QKLD (3*CC)      // qkv packed row stride = 768
#define NEG_BIG (-1e30f)

typedef _Float16 h16;
typedef __attribute__((ext_vector_type(8))) _Float16 half8;
typedef __attribute__((ext_vector_type(4))) float f32x4;
typedef __attribute__((ext_vector_type(16))) float f32x16;

// ---------------- async global->LDS, 16B per lane ----------------
__device__ __forceinline__ void gload16(const h16* g, h16* l) {
    __builtin_amdgcn_global_load_lds((const __attribute__((address_space(1))) void*)g,
                                     (__attribute__((address_space(3))) void*)l, 16, 0, 0);
}

// stage ROWS x 64 h16 chunk into lds[ROWS][64] with piece-XOR swizzle
template<int ROWS>
__device__ __forceinline__ void stage_rows(const h16* __restrict__ src, int ld,
    int row0, int c0, h16* lds, int tid)
{
    int w = tid >> 6;
    #pragma unroll
    for (int t = 0; t < ROWS/32; ++t) {
        int slot = t*256 + tid;
        int row = slot >> 3;
        int pp  = slot & 7;
        int piece = pp ^ (row & 7);
        gload16(src + (size_t)(row0 + row)*ld + c0 + piece*8,
                lds + (t*256 + w*64)*8);
    }
}

// read 8 contiguous h16 (logical k-piece pl) of LDS row
__device__ __forceinline__ half8 frag_ld(const h16* lds, int row, int pl) {
    return *(const half8*)(lds + row*64 + ((pl ^ (row & 7))*8));
}

// ---------------- weight transpose+convert: W[K,N] f32 -> WT[N,K] f16 ----------------
__global__ __launch_bounds__(256) void pct_wtrans(const float* __restrict__ W,
    h16* __restrict__ WT, int K, int N, int dstride)
{
    __shared__ h16 t[32][33];
    const float* Wl = W + (size_t)blockIdx.z*K*N;
    h16* WTl = WT + (size_t)blockIdx.z*dstride;
    int k0 = blockIdx.x*32, n0 = blockIdx.y*32;
    int tx = threadIdx.x & 31, ty = threadIdx.x >> 5;
    #pragma unroll
    for (int i = ty; i < 32; i += 8)
        t[i][tx] = (h16)Wl[(size_t)(k0+i)*N + n0 + tx];
    __syncthreads();
    #pragma unroll
    for (int i = ty; i < 32; i += 8)
        WTl[(size_t)(n0+i)*K + k0 + tx] = t[tx][i];
}

// ---------------- pack q/k/v biases into [NLAYER][768] ----------------
__global__ __launch_bounds__(256) void pct_bias3(const float* __restrict__ bq,
    const float* __restrict__ bk, const float* __restrict__ bv, float* __restrict__ o)
{
    int l = blockIdx.x, c = threadIdx.x;
    o[l*QKLD + c]        = bq[l*CC + c];
    o[l*QKLD + CC + c]   = bk[l*CC + c];
    o[l*QKLD + 2*CC + c] = bv[l*CC + c];
}

// ---------------- embed: [B,N,3] @ [3,256] + b -> f16 ----------------
__global__ __launch_bounds__(256) void pct_embed(const float* __restrict__ inp,
    const float* __restrict__ w0, const float* __restrict__ b0, h16* __restrict__ out)
{
    int r = blockIdx.x, c = threadIdx.x;
    float a0 = inp[r*3+0], a1 = inp[r*3+1], a2 = inp[r*3+2];
    out[(size_t)r*CC + c] = (h16)(b0[c] + a0*w0[c] + a1*w0[CC+c] + a2*w0[2*CC+c]);
}

// ---------------- column stats over points axis (half8 vectorized) ----------------
__global__ __launch_bounds__(256) void pct_colstat(const h16* __restrict__ x, int ldx,
    float* __restrict__ sums)
{
    __shared__ float red[2][8][256];
    int b = blockIdx.x, blk = blockIdx.y;
    int rt = threadIdx.x >> 5;
    int cg = (threadIdx.x & 31) * 8;
    const h16* p = x + ((size_t)b*NN + (size_t)blk*64 + rt)*ldx + cg;
    float s1[8] = {0,0,0,0,0,0,0,0}, s2[8] = {0,0,0,0,0,0,0,0};
    #pragma unroll
    for (int i = 0; i < 8; ++i) {
        half8 v = *(const half8*)(p + (size_t)i*8*ldx);
        #pragma unroll
        for (int j = 0; j < 8; ++j) { float f = (float)v[j]; s1[j] += f; s2[j] += f*f; }
    }
    #pragma unroll
    for (int j = 0; j < 8; ++j) { red[0][rt][cg+j] = s1[j]; red[1][rt][cg+j] = s2[j]; }
    __syncthreads();
    int c = threadIdx.x;
    float t1 = 0.f, t2 = 0.f;
    #pragma unroll
    for (int r = 0; r < 8; ++r) { t1 += red[0][r][c]; t2 += red[1][r][c]; }
    atomicAdd(&sums[(b*CC + c)*2 + 0], t1);
    atomicAdd(&sums[(b*CC + c)*2 + 1], t2);
}

// ---------------- apply LN (stats over points), optional relu + residual (half8) ----------------
__global__ __launch_bounds__(256) void pct_lnapply(const h16* __restrict__ x, int ldx,
    const float* __restrict__ sums, const float* __restrict__ scale, const float* __restrict__ bias,
    const h16* __restrict__ res, int ldr, h16* __restrict__ out, int ldo,
    int do_relu)
{
    int r = blockIdx.x*8 + (threadIdx.x >> 5);
    int cg = (threadIdx.x & 31) * 8;
    int b = r / NN;
    half8 xv = *(const half8*)(x + (size_t)r*ldx + cg);
    half8 rv;
    if (res) rv = *(const half8*)(res + (size_t)r*ldr + cg);
    half8 ov;
    #pragma unroll
    for (int j = 0; j < 8; ++j) {
        int c = cg + j;
        float s1 = sums[(b*CC + c)*2], s2 = sums[(b*CC + c)*2 + 1];
        float mu  = s1 * (1.f/NN);
        float var = s2 * (1.f/NN) - mu*mu;
        float rstd = rsqrtf(var + 1e-6f);
        float y = ((float)xv[j] - mu) * rstd * scale[c] + bias[c];
        if (do_relu) y = fmaxf(y, 0.f);
        if (res) y += (float)rv[j];
        ov[j] = (h16)y;
    }
    *(half8*)(out + (size_t)r*ldo + cg) = ov;
}

// ---------------- f16 MFMA GEMM (NT): out[m,n] = rowS(m)*(sum_k A[m,k]*WT[n,k]) + bias[n] ----------------
template<int BN, bool OUT_F32>
__global__ __launch_bounds__(256) void pct_gemm_f16(
    const h16* __restrict__ A, int lda,
    const h16* __restrict__ WT, const float* __restrict__ bias,
    void* __restrict__ outp, int ldo, int K, const float* __restrict__ rowS)
{
    constexpr int BJ = BN/2;
    constexpr int NF = BJ/16;
    __shared__ __align__(16) h16 Asm[128*64];
    __shared__ __align__(16) h16 Bsm[BN*64];
    const int tid = threadIdx.x;
    const int lane = tid & 63, w = tid >> 6;
    const int ln = lane & 15, lq = lane >> 4;
    const int wr = w >> 1, wc = w & 1;
    const int m0 = blockIdx.x*128, n0 = blockIdx.y*BN;
    f32x4 acc[4][NF];
    #pragma unroll
    for (int i = 0; i < 4; ++i)
        #pragma unroll
        for (int j = 0; j < NF; ++j) acc[i][j] = (f32x4){0.f,0.f,0.f,0.f};
    for (int k0 = 0; k0 < K; k0 += 64) {
        stage_rows<128>(A, lda, m0, k0, Asm, tid);
        stage_rows<BN>(WT, K, n0, k0, Bsm, tid);
        __syncthreads();
        #pragma unroll
        for (int kk = 0; kk < 2; ++kk) {
            half8 af[4], bfr[NF];
            #pragma unroll
            for (int i = 0; i < 4; ++i) af[i] = frag_ld(Asm, wr*64 + i*16 + ln, kk*4 + lq);
            #pragma unroll
            for (int j = 0; j < NF; ++j) bfr[j] = frag_ld(Bsm, wc*BJ + j*16 + ln, kk*4 + lq);
            #pragma unroll
            for (int i = 0; i < 4; ++i)
                #pragma unroll
                for (int j = 0; j < NF; ++j)
                    acc[i][j] = __builtin_amdgcn_mfma_f32_16x16x32_f16(af[i], bfr[j], acc[i][j], 0, 0, 0);
        }
        __syncthreads();
    }
    #pragma unroll
    for (int j = 0; j < NF; ++j) {
        int col = n0 + wc*BJ + j*16 + ln;
        float bv = bias[col];
        #pragma unroll
        for (int i = 0; i < 4; ++i) {
            #pragma unroll
            for (int r = 0; r < 4; ++r) {
                int row = m0 + wr*64 + i*16 + lq*4 + r;
                float sc = 1.f;
                if (rowS) { float s = rowS[row]; sc = s / (1e-9f + s); }
                float v = acc[i][j][r] * sc + bv;
                if (OUT_F32) ((float*)outp)[(size_t)row*ldo + col] = v;
                else ((h16*)outp)[(size_t)row*ldo + col] = (h16)v;
            }
        }
    }
}

// ---------------- pass A: row max/sumexp of Q@K^T ----------------
// Q resident in regs (B operand, m on lane axis); K streamed via double-buffered LDS.
// grid (BB, NN/128, SPL); 4 waves; wave w owns m = m0+w*32+ln2 (h halves split n).
__global__ __launch_bounds__(256) void attn_rowstats(const h16* __restrict__ QKV,
    float2* __restrict__ part)
{
    __shared__ __align__(16) h16 Ks[2][128*64];
    const int b = blockIdx.x, mt = blockIdx.y, sp = blockIdx.z;
    const int tid = threadIdx.x;
    const int lane = tid & 63, w = tid >> 6;
    const int ln2 = lane & 31, h = lane >> 5;
    const h16* qb = QKV + (size_t)b*NN*QKLD;
    const h16* kb = qb + CC;
    const int m0 = mt*128;
    // resident Q: this lane's m-row, all K=256, h-half slices
    const h16* qrow = qb + (size_t)(m0 + w*32 + ln2)*QKLD + h*8;
    half8 qreg[16];
    #pragma unroll
    for (int i = 0; i < 16; ++i) qreg[i] = *(const half8*)(qrow + i*16);

    const int nbeg = sp*(NN/SPL);
    const int NT = (NN/SPL)/128;      // 2 n-tiles
    float rm = NEG_BIG, rs = 0.f;

    // prefetch chunk 0
    stage_rows<128>(kb, QKLD, nbeg, 0, Ks[0], tid);
    int id = 0;
    for (int t = 0; t < NT; ++t) {
        f32x16 acc[4];
        #pragma unroll
        for (int j = 0; j < 4; ++j) acc[j] = (f32x16)(0.f);
        #pragma unroll
        for (int c = 0; c < 4; ++c, ++id) {
            __syncthreads();                       // chunk id staged
            if (id + 1 < NT*4)                     // prefetch next chunk into other buffer
                stage_rows<128>(kb, QKLD, nbeg + ((id+1) >> 2)*128, ((id+1) & 3)*64,
                                Ks[(id+1) & 1], tid);
            const h16* buf = Ks[id & 1];
            #pragma unroll
            for (int kk = 0; kk < 4; ++kk) {
                half8 bq = qreg[c*4 + kk];
                #pragma unroll
                for (int j = 0; j < 4; ++j) {
                    half8 af = frag_ld(buf, j*32 + ln2, kk*2 + h);
                    acc[j] = __builtin_amdgcn_mfma_f32_32x32x16_f16(af, bq, acc[j], 0, 0, 0);
                }
            }
        }
        // register-only tail (overlaps the in-flight prefetch): 64 values, one m per lane
        float tm = NEG_BIG;
        #pragma unroll
        for (int j = 0; j < 4; ++j)
            #pragma unroll
            for (int g = 0; g < 16; g += 2)
                tm = fmaxf(tm, fmaxf(acc[j][g], acc[j][g+1]));
        if (tm > rm) { rs *= __expf(rm - tm); rm = tm; }
        float s = 0.f;
        #pragma unroll
        for (int j = 0; j < 4; ++j)
            #pragma unroll
            for (int g = 0; g < 16; ++g)
                s += __expf(acc[j][g] - rm);
        rs += s;
    }
    // merge the two h-halves (same m, disjoint n subsets)
    float mo = __shfl_xor(rm, 32, 64);
    float so = __shfl_xor(rs, 32, 64);
    float mn = fmaxf(rm, mo);
    float sm = rs*__expf(rm - mn) + so*__expf(mo - mn);
    if (lane < 32) {
        int m = m0 + w*32 + ln2;
        part[((size_t)b*NN + m)*SPL + sp] = make_float2(mn, sm);
    }
}

// ---------------- combine SPL split row stats; store (rmax, 1/rsum) ----------------
__global__ __launch_bounds__(256) void pct_rowcomb(const float2* __restrict__ part,
    float2* __restrict__ rstat)
{
    int idx = blockIdx.x*256 + threadIdx.x;
    const float2* p = part + (size_t)idx*SPL;
    float m = NEG_BIG;
    #pragma unroll
    for (int s = 0; s < SPL; ++s) m = fmaxf(m, p[s].x);
    float sum = 0.f;
    #pragma unroll
    for (int s = 0; s < SPL; ++s) sum += p[s].y * __expf(p[s].x - m);
    rstat[idx] = make_float2(m, 1.0f / sum);
}

// ---------------- pass B: column sums of softmax ----------------
// K resident in regs (B operand, n on lane axis); Q streamed via double-buffered LDS.
__global__ __launch_bounds__(256) void attn_colsums(const h16* __restrict__ QKV,
    const float2* __restrict__ rstat, float* __restrict__ S)
{
    __shared__ __align__(16) h16 Qs[2][128*64];
    const int b = blockIdx.x, nt = blockIdx.y, sp = blockIdx.z;
    const int tid = threadIdx.x;
    const int lane = tid & 63, w = tid >> 6;
    const int ln2 = lane & 31, h = lane >> 5;
    const h16* qb = QKV + (size_t)b*NN*QKLD;
    const h16* kb = qb + CC;
    const float2* rst = rstat + (size_t)b*NN;
    const int n0 = nt*128;
    const h16* krow = kb + (size_t)(n0 + w*32 + ln2)*QKLD + h*8;
    half8 kreg[16];
    #pragma unroll
    for (int i = 0; i < 16; ++i) kreg[i] = *(const half8*)(krow + i*16);

    const int mbeg = sp*(NN/SPL);
    const int NT = (NN/SPL)/128;
    float cs = 0.f;

    stage_rows<128>(qb, QKLD, mbeg, 0, Qs[0], tid);
    int id = 0;
    for (int t = 0; t < NT; ++t) {
        f32x16 acc[4];
        #pragma unroll
        for (int j = 0; j < 4; ++j) acc[j] = (f32x16)(0.f);
        #pragma unroll
        for (int c = 0; c < 4; ++c, ++id) {
            __syncthreads();
            if (id + 1 < NT*4)
                stage_rows<128>(qb, QKLD, mbeg + ((id+1) >> 2)*128, ((id+1) & 3)*64,
                                Qs[(id+1) & 1], tid);
            const h16* buf = Qs[id & 1];
            #pragma unroll
            for (int kk = 0; kk < 4; ++kk) {
                half8 bk = kreg[c*4 + kk];
                #pragma unroll
                for (int j = 0; j < 4; ++j) {
                    half8 af = frag_ld(buf, j*32 + ln2, kk*2 + h);
                    acc[j] = __builtin_amdgcn_mfma_f32_32x32x16_f16(af, bk, acc[j], 0, 0, 0);
                }
            }
        }
        // tail: cs += exp(acc - rmax[m]) / rsum[m];  m = mtile + j*32 + rowfn(g,h)
        int mt0 = mbeg + t*128;
        #pragma unroll
        for (int j = 0; j < 4; ++j) {
            #pragma unroll
            for (int g = 0; g < 16; ++g) {
                int m = mt0 + j*32 + (g & 3) + 8*(g >> 2) + 4*h;
                float2 st = rst[m];
                cs += __expf(acc[j][g] - st.x) * st.y;
            }
        }
    }
    cs += __shfl_xor(cs, 32, 64);
    if (lane < 32) {
        int n = n0 + w*32 + ln2;
        atomicAdd(&S[(size_t)b*NN + n], cs);
    }
}

extern "C" void kernel_launch(void* const* d_in, const int* in_sizes, int n_in,
                              void* d_out, int out_size, void* d_ws, size_t ws_size,
                              hipStream_t stream)
{
    const float* inp  = (const float*)d_in[0];
    const float* w0   = (const float*)d_in[1];
    const float* b0   = (const float*)d_in[2];
    const float* ln0s = (const float*)d_in[3];
    const float* ln0b = (const float*)d_in[4];
    const float* w1   = (const float*)d_in[5];
    const float* b1   = (const float*)d_in[6];
    const float* ln1s = (const float*)d_in[7];
    const float* ln1b = (const float*)d_in[8];
    const float* wq   = (const float*)d_in[9];
    const float* bq   = (const float*)d_in[10];
    const float* wk   = (const float*)d_in[11];
    const float* bk   = (const float*)d_in[12];
    const float* wv   = (const float*)d_in[13];
    const float* bv   = (const float*)d_in[14];
    const float* wo   = (const float*)d_in[15];
    const float* bo   = (const float*)d_in[16];
    const float* alns = (const float*)d_in[17];
    const float* alnb = (const float*)d_in[18];
    const float* wf   = (const float*)d_in[19];
    const float* bfb  = (const float*)d_in[20];
    float* out = (float*)d_out;

    // workspace layout
    char* p = (char*)d_ws;
    auto alloc = [&](size_t bytes) { char* r = p; p += (bytes + 255) & ~255ULL; return r; };
    h16* t0    = (h16*)alloc((size_t)RR*CC*2);
    h16* t1    = (h16*)alloc((size_t)RR*CC*2);
    h16* t2    = (h16*)alloc((size_t)RR*CC*2);
    h16* x1    = (h16*)alloc((size_t)RR*CC*2);
    h16* qkv   = (h16*)alloc((size_t)RR*QKLD*2);
    h16* oh    = (h16*)alloc((size_t)RR*CC*2);
    h16* xcat  = (h16*)alloc((size_t)RR*FF*2);
    h16* w1T   = (h16*)alloc((size_t)CC*CC*2);
    h16* wqkvT = (h16*)alloc((size_t)NLAYER*QKLD*CC*2);
    h16* woT   = (h16*)alloc((size_t)NLAYER*CC*CC*2);
    h16* wfT   = (h16*)alloc((size_t)FF*FF*2);
    float* bqkv  = (float*)alloc((size_t)NLAYER*QKLD*4);
    float2* part  = (float2*)alloc((size_t)RR*SPL*8);
    float2* rstat = (float2*)alloc((size_t)RR*8);
    float* Ssum  = (float*)alloc((size_t)NLAYER*RR*4);   // zeroed below
    float* lns   = (float*)alloc((size_t)6*BB*CC*2*4);   // zeroed below (adjacent)

    dim3 blk(256);

    // zero Ssum..lns span in one memset (adjacent in layout)
    hipMemsetAsync(Ssum, 0, (size_t)((char*)(lns + 6*BB*CC*2) - (char*)Ssum), stream);

    // weight transpose+convert (+pack q/k/v)
    pct_wtrans<<<dim3(CC/32, CC/32, 1), blk, 0, stream>>>(w1, w1T, CC, CC, CC*CC);
    pct_wtrans<<<dim3(CC/32, CC/32, NLAYER), blk, 0, stream>>>(wq, wqkvT,            CC, CC, QKLD*CC);
    pct_wtrans<<<dim3(CC/32, CC/32, NLAYER), blk, 0, stream>>>(wk, wqkvT + CC*CC,    CC, CC, QKLD*CC);
    pct_wtrans<<<dim3(CC/32, CC/32, NLAYER), blk, 0, stream>>>(wv, wqkvT + 2*CC*CC,  CC, CC, QKLD*CC);
    pct_wtrans<<<dim3(CC/32, CC/32, NLAYER), blk, 0, stream>>>(wo, woT, CC, CC, CC*CC);
    pct_wtrans<<<dim3(FF/32, FF/32, 1), blk, 0, stream>>>(wf, wfT, FF, FF, FF*FF);
    pct_bias3<<<NLAYER, blk, 0, stream>>>(bq, bk, bv, bqkv);

    // pre-conv stack
    pct_embed<<<RR, blk, 0, stream>>>(inp, w0, b0, t0);
    pct_colstat<<<dim3(BB,64), blk, 0, stream>>>(t0, CC, lns + 0*BB*CC*2);
    pct_lnapply<<<RR/8, blk, 0, stream>>>(t0, CC, lns + 0*BB*CC*2, ln0s, ln0b, nullptr, 0, t1, CC, 0);
    pct_gemm_f16<64,false><<<dim3(RR/128, CC/64), blk, 0, stream>>>(t1, CC, w1T, b1, t2, CC, CC, nullptr);
    pct_colstat<<<dim3(BB,64), blk, 0, stream>>>(t2, CC, lns + 1*BB*CC*2);
    pct_lnapply<<<RR/8, blk, 0, stream>>>(t2, CC, lns + 1*BB*CC*2, ln1s, ln1b, nullptr, 0, x1, CC, 0);

    const h16* xin = x1; int ldx = CC;
    for (int i = 0; i < NLAYER; ++i) {
        // fused q/k/v GEMM -> qkv[RR][768]
        pct_gemm_f16<64,false><<<dim3(RR/128, QKLD/64), blk, 0, stream>>>(
            xin, ldx, wqkvT + (size_t)i*QKLD*CC, bqkv + i*QKLD, qkv, QKLD, CC, nullptr);

        attn_rowstats<<<dim3(BB, NN/128, SPL), blk, 0, stream>>>(qkv, part);
        pct_rowcomb<<<RR/256, blk, 0, stream>>>(part, rstat);
        attn_colsums<<<dim3(BB, NN/128, SPL), blk, 0, stream>>>(qkv, rstat, Ssum + (size_t)i*RR);

        // wo GEMM on v (rows scaled by col[m] in epilogue)
        pct_gemm_f16<64,false><<<dim3(RR/128, CC/64), blk, 0, stream>>>(
            qkv + 2*CC, QKLD, woT + (size_t)i*CC*CC, bo + i*CC, oh, CC, CC, Ssum + (size_t)i*RR);

        pct_colstat<<<dim3(BB,64), blk, 0, stream>>>(oh, CC, lns + (2+i)*BB*CC*2);
        pct_lnapply<<<RR/8, blk, 0, stream>>>(oh, CC, lns + (2+i)*BB*CC*2, alns + i*CC, alnb + i*CC,
                                              xin, ldx, xcat + i*CC, FF, 1);
        xin = xcat + i*CC; ldx = FF;
    }

    pct_gemm_f16<128,true><<<dim3(RR/128, FF/128), blk, 0, stream>>>(xcat, FF, wfT, bfb, out, FF, FF, nullptr);
}